// Round 4
// baseline (303.622 us; speedup 1.0000x reference)
//
#include <hip/hip_runtime.h>
#include <math.h>
#include <stdint.h>

// MoE: B=8192 tokens, D_IN=1024, 8 experts, D_EXP=1024, top-2.
// Pipeline: prep (gating+x-cast | w1 transpose | w2 transpose | rowTok init)
// -> slot kernel (single block, vectorized; 128-row tiles)
// -> gemm1/gemm2: 128x128 BK=32 double-buffered bf16 MFMA GEMM, counted
//    vmcnt(4), 32KB LDS (4 blocks/CU), pair-XOR LDS swizzle (conflict-free
//    ds_read_b128), grid (8 panels, 136 tiles): panel == XCD -> B L2-resident
// -> weighted combine.

#define NTOK   8192
#define DIN    1024
#define NEXP   8
#define DEXP   1024
#define MAXROWS 17408   // 16384 assignments + per-expert pad to 128 (17*1024)
#define MAXT   136      // max 128-row tiles

typedef __bf16 bf16x8_t __attribute__((ext_vector_type(8)));
typedef float f32x4 __attribute__((ext_vector_type(4)));

__device__ __forceinline__ unsigned short f2bf(float f) {
  union { float f; unsigned int u; } v; v.f = f;
  unsigned int u = v.u;
  u += 0x7fffu + ((u >> 16) & 1u);   // round-to-nearest-even
  return (unsigned short)(u >> 16);
}

__device__ __forceinline__ float bf2f(unsigned short s) {
  union { unsigned int u; float f; } v; v.u = ((unsigned int)s) << 16;
  return v.f;
}

__device__ __forceinline__ void async16(const void* g, void* l) {
  __builtin_amdgcn_global_load_lds((const __attribute__((address_space(1))) void*)g,
                                   (__attribute__((address_space(3))) void*)l, 16, 0, 0);
}

// fast GELU: tanh form via sigmoid, max abs err ~3e-4 (threshold is 5.7e-2)
__device__ __forceinline__ float gelu_fast(float v) {
  float u = v * (1.5957691216057308f + 0.07135481627f * v * v);
  return v * (1.0f / (1.0f + __expf(-u)));
}

// ---- 64x64 fp32->bf16 transpose tile (pad-65 LDS, 2-way free banks) ----
__device__ __forceinline__ void transpose_tile(const float* s, unsigned short* d,
                                               float* tile, int tid) {
  int a = tid & 15, r0 = tid >> 4;
  #pragma unroll
  for (int p = 0; p < 4; ++p) {
    int r = r0 + p * 16;
    float4 v = *(const float4*)(s + (size_t)r * 1024 + a * 4);
    tile[r * 65 + a * 4 + 0] = v.x;
    tile[r * 65 + a * 4 + 1] = v.y;
    tile[r * 65 + a * 4 + 2] = v.z;
    tile[r * 65 + a * 4 + 3] = v.w;
  }
  __syncthreads();
  #pragma unroll
  for (int p = 0; p < 4; ++p) {
    int nr = r0 + p * 16;
    ushort4 o;
    o.x = f2bf(tile[(a * 4 + 0) * 65 + nr]);
    o.y = f2bf(tile[(a * 4 + 1) * 65 + nr]);
    o.z = f2bf(tile[(a * 4 + 2) * 65 + nr]);
    o.w = f2bf(tile[(a * 4 + 3) * 65 + nr]);
    *(ushort4*)(d + (size_t)nr * 1024 + a * 4) = o;
  }
}

// ---- prep: [0,2048) gating+x-cast | [2048,4096) w1T | [4096,6144) w2T
//      | [6144,6161) rowTok init
__global__ __launch_bounds__(256) void prep_kernel(const float* __restrict__ x,
                                                   const float* __restrict__ gw,
                                                   const float* __restrict__ w1,
                                                   const float* __restrict__ w2,
                                                   unsigned short* __restrict__ xbf,
                                                   unsigned short* __restrict__ w1T,
                                                   unsigned short* __restrict__ w2T,
                                                   float* __restrict__ outGate,
                                                   int* __restrict__ topE,
                                                   float* __restrict__ topW,
                                                   int* __restrict__ rowTok) {
  __shared__ __align__(16) char smem[32768];
  int b = blockIdx.x;
  int tid = threadIdx.x;
  if (b >= 6144) {
    int base = (b - 6144) * 1024 + tid * 4;
    *(int4*)(rowTok + base) = make_int4(-1, -1, -1, -1);
    return;
  }
  if (b >= 2048) {
    // ---- weight transpose+cast: [e][k][n] fp32 -> [e][n][k] bf16
    int idx = b - 2048;                      // 0..4095
    const float* src = (idx < 2048) ? w1 : w2;
    unsigned short* dst = (idx < 2048) ? w1T : w2T;
    idx &= 2047;
    int e = idx >> 8, rest = idx & 255, kt = rest >> 4, nt = rest & 15;
    const float* s = src + (size_t)e * DIN * DEXP + (size_t)kt * 64 * 1024 + nt * 64;
    unsigned short* d = dst + (size_t)e * DIN * DEXP + (size_t)nt * 64 * 1024 + kt * 64;
    transpose_tile(s, d, (float*)smem, tid);
    return;
  }
  // ---- gating + x cast: gw staged transposed in LDS, one token per wave
  float (*gwT)[1024] = (float(*)[1024])smem;   // 32KB
  #pragma unroll
  for (int it = 0; it < 8; ++it) {
    int idx = it * 256 + tid;         // 0..2047 float4 chunks of gw[1024][8]
    int fk = idx >> 1;
    int e0 = (idx & 1) * 4;
    float4 g = *(const float4*)(gw + fk * 8 + e0);
    gwT[e0 + 0][fk] = g.x; gwT[e0 + 1][fk] = g.y;
    gwT[e0 + 2][fk] = g.z; gwT[e0 + 3][fk] = g.w;
  }
  __syncthreads();

  int lane = tid & 63, wv = tid >> 6;
  int t = b * 4 + wv;
  const float4* xr = (const float4*)(x + (size_t)t * 1024);
  ushort4* xo = (ushort4*)(xbf + (size_t)t * 1024);
  double acc[NEXP];
  #pragma unroll
  for (int e = 0; e < NEXP; ++e) acc[e] = 0.0;
  #pragma unroll
  for (int j = 0; j < 4; ++j) {
    int q = lane + 64 * j;
    float4 v = xr[q];
    ushort4 r;
    r.x = f2bf(v.x); r.y = f2bf(v.y); r.z = f2bf(v.z); r.w = f2bf(v.w);
    xo[q] = r;
    float vv[4] = {v.x, v.y, v.z, v.w};
    #pragma unroll
    for (int e = 0; e < NEXP; ++e) {
      float4 g = *(const float4*)&gwT[e][4 * q];
      acc[e] += (double)vv[0] * (double)g.x;
      acc[e] += (double)vv[1] * (double)g.y;
      acc[e] += (double)vv[2] * (double)g.z;
      acc[e] += (double)vv[3] * (double)g.w;
    }
  }
  #pragma unroll
  for (int off = 32; off > 0; off >>= 1) {
    #pragma unroll
    for (int e = 0; e < NEXP; ++e) acc[e] += __shfl_xor(acc[e], off);
  }
  if (lane == 0) {
    int e0 = 0; double v0 = acc[0];
    #pragma unroll
    for (int e = 1; e < NEXP; ++e) if (acc[e] > v0) { v0 = acc[e]; e0 = e; }
    int e1 = -1; double v1 = -1e300;
    #pragma unroll
    for (int e = 0; e < NEXP; ++e) if (e != e0 && acc[e] > v1) { v1 = acc[e]; e1 = e; }
    float ex = expf((float)(v1 - v0));
    float inv = 1.0f / (1.0f + ex);
    float w0 = inv, w1v = ex * inv;
    float g8[8];
    #pragma unroll
    for (int e = 0; e < NEXP; ++e) g8[e] = 0.f;
    g8[e0] = w0; g8[e1] = w1v;
    float4* gp = (float4*)(outGate + t * 8);
    gp[0] = *(float4*)&g8[0];
    gp[1] = *(float4*)&g8[4];
    topE[t * 2 + 0] = e0; topE[t * 2 + 1] = e1;
    topW[t * 2 + 0] = w0; topW[t * 2 + 1] = w1v;
  }
}

// ---------------- slot assign: one block, 128-row tiles ----------------
__global__ __launch_bounds__(1024) void slot_kernel(const int* __restrict__ topE,
                                                    int* __restrict__ topRow,
                                                    int* __restrict__ rowTok,
                                                    int* __restrict__ tileExpert,
                                                    int* __restrict__ tileRowBase) {
  __shared__ int wtot[16][NEXP];
  __shared__ int wbase[16][NEXP];
  __shared__ int soff[NEXP];
  int tid = threadIdx.x;
  int lane = tid & 63, wv = tid >> 6;
  int a0 = tid * 16;
  unsigned long long pk = 0ull;
  int cnt[NEXP];
  #pragma unroll
  for (int e = 0; e < NEXP; ++e) cnt[e] = 0;
  #pragma unroll
  for (int i = 0; i < 4; ++i) {
    int4 ev = *(const int4*)(topE + a0 + i * 4);    // coalesced 16B loads
    int e4[4] = {ev.x, ev.y, ev.z, ev.w};
    #pragma unroll
    for (int m = 0; m < 4; ++m) {
      int e = e4[m];
      pk |= (unsigned long long)e << ((i * 4 + m) * 4);
      cnt[e]++;
    }
  }
  int excl[NEXP];
  #pragma unroll
  for (int e = 0; e < NEXP; ++e) {
    int v = cnt[e], sum = v;
    #pragma unroll
    for (int d = 1; d < 64; d <<= 1) {
      int u = __shfl_up(sum, d);
      if (lane >= d) sum += u;
    }
    excl[e] = sum - v;
    if (lane == 63) wtot[wv][e] = sum;
  }
  __syncthreads();
  if (tid == 0) {
    int counts[NEXP];
    for (int e = 0; e < NEXP; ++e) {
      int s = 0;
      for (int w = 0; w < 16; ++w) { wbase[w][e] = s; s += wtot[w][e]; }
      counts[e] = s;
    }
    int row = 0, tl = 0;
    for (int e = 0; e < NEXP; ++e) {
      soff[e] = row;
      int nt = (counts[e] + 127) >> 7;      // 128-row tiles
      for (int i = 0; i < nt; ++i) { tileExpert[tl] = e; tileRowBase[tl] = row + i * 128; ++tl; }
      row += nt << 7;
    }
    for (; tl < MAXT; ++tl) tileExpert[tl] = -1;
  }
  __syncthreads();
  int base[NEXP], run[NEXP];
  #pragma unroll
  for (int e = 0; e < NEXP; ++e) { base[e] = soff[e] + wbase[wv][e] + excl[e]; run[e] = 0; }
  for (int i = 0; i < 16; ++i) {
    int e = (int)((pk >> (i * 4)) & 7ull);
    int row = base[e] + run[e]++;
    rowTok[row] = (a0 + i) >> 1;
    topRow[a0 + i] = row;
  }
}

// ---------------- 128x128 BK=32 double-buffered MoE GEMM body ----------------
// Pair-XOR swizzle: LDS physical layout per 16-row group = 8 row-PAIRS of
// 128B; within pair p, position pos holds logical (rowbit=L>>2, chunk=L&3)
// with L = pos ^ p.  ds_read_b128 per 16-lane phase then covers all 8
// bank-quads exactly 2x -> conflict-free.  Staging swizzles the GLOBAL
// source per lane (LDS dest stays lane-linear for global_load_lds).
template <bool GATHER, bool GELU>
__device__ __forceinline__ void moe_gemm_body(
    const unsigned short* __restrict__ Asrc,
    const unsigned short* __restrict__ Wt,
    const float* __restrict__ bias,
    const int* __restrict__ tileExpert,
    const int* __restrict__ tileRowBase,
    const int* __restrict__ rowTok,
    unsigned short* __restrict__ Out,
    unsigned short* sm) {
  int e = tileExpert[blockIdx.y];
  if (e < 0) return;
  int rowBase = tileRowBase[blockIdx.y];
  int n0 = blockIdx.x * 128;

  int tid = threadIdx.x;
  int lane = tid & 63, wv = tid >> 6;
  int wr = wv >> 1, wc = wv & 1;             // 2M x 2N wave grid

  // staging decomposition (per wave: 16 rows = 8 pairs x 8 positions)
  int p = lane >> 3, pos = lane & 7;
  int L = pos ^ p;
  int rowoff = wv * 16 + p * 2 + (L >> 2);   // row within 64-row half
  int qsw = L & 3;                           // logical 16B k-chunk to fetch

  // read decomposition
  int rsel = lane & 15, quad = lane >> 4;    // quad 0..3
  int prow = rsel >> 1;
  int co = (((rsel & 1) * 4 + quad) ^ prow) * 8 + prow * 64;  // shorts

  int arow[2];
  #pragma unroll
  for (int j = 0; j < 2; ++j) {
    int r = rowBase + j * 64 + rowoff;
    if (GATHER) { int tk = rowTok[r]; arow[j] = tk < 0 ? 0 : tk; }
    else arow[j] = r;
  }
  const unsigned short* Bsrc = Wt + (size_t)e * 1024 * 1024;

  auto stage = [&](int T) {
    int kk = T * 32;
    int selB = (T & 1) * 16384;              // byte offset of buffer
    #pragma unroll
    for (int j = 0; j < 2; ++j) {
      int ab = __builtin_amdgcn_readfirstlane(selB + j * 4096 + wv * 1024);
      async16(Asrc + (size_t)arow[j] * 1024 + kk + qsw * 8, (char*)sm + ab);
      async16(Bsrc + (size_t)(n0 + j * 64 + rowoff) * 1024 + kk + qsw * 8,
              (char*)sm + ab + 8192);
    }
  };

  f32x4 acc[4][4] = {};

  // prologue: tiles 0,1 in flight (8 loads); wait tile 0 (4 retired)
  stage(0);
  stage(1);
  asm volatile("s_waitcnt vmcnt(4)" ::: "memory");
  __builtin_amdgcn_s_barrier();

  for (int t = 0; t < 32; ++t) {
    const unsigned short* sA = sm + (t & 1) * 8192;   // shorts
    const unsigned short* sB = sA + 4096;
    bf16x8_t af[4], bf[4];
    #pragma unroll
    for (int mi = 0; mi < 4; ++mi)
      af[mi] = *(const bf16x8_t*)&sA[wr * 2048 + mi * 512 + co];
    #pragma unroll
    for (int ni = 0; ni < 4; ++ni)
      bf[ni] = *(const bf16x8_t*)&sB[wc * 2048 + ni * 512 + co];
    __builtin_amdgcn_s_setprio(1);
    #pragma unroll
    for (int mi = 0; mi < 4; ++mi)
      #pragma unroll
      for (int ni = 0; ni < 4; ++ni)
        acc[mi][ni] = __builtin_amdgcn_mfma_f32_16x16x32_bf16(af[mi], bf[ni], acc[mi][ni], 0, 0, 0);
    __builtin_amdgcn_s_setprio(0);
    __builtin_amdgcn_s_barrier();            // all waves done reading buf (t&1)
    if (t + 2 < 32) {
      stage(t + 2);                          // refill freed buffer
      asm volatile("s_waitcnt vmcnt(4)" ::: "memory");  // tile t+1 landed
    } else {
      asm volatile("s_waitcnt vmcnt(0)" ::: "memory");
    }
    __builtin_amdgcn_s_barrier();            // buf (t+1)&1 valid for all
  }

  // epilogue: bias (+gelu) -> bf16 -> LDS (128x128) -> coalesced store
  float bv[4];
  #pragma unroll
  for (int ni = 0; ni < 4; ++ni)
    bv[ni] = bias[e * 1024 + n0 + wc * 64 + ni * 16 + rsel];
  #pragma unroll
  for (int mi = 0; mi < 4; ++mi)
    #pragma unroll
    for (int ni = 0; ni < 4; ++ni)
      #pragma unroll
      for (int r = 0; r < 4; ++r) {
        int m = wr * 64 + mi * 16 + quad * 4 + r;
        int n = wc * 64 + ni * 16 + rsel;
        float v = acc[mi][ni][r] + bv[ni];
        if (GELU) v = gelu_fast(v);
        sm[m * 128 + n] = f2bf(v);
      }
  __syncthreads();
  #pragma unroll
  for (int i = 0; i < 8; ++i) {
    int idx = i * 4096 + tid * 16;           // byte offset in 32KB
    int m = idx >> 8, cb = idx & 255;        // 256B per row
    *(uint4*)(Out + (size_t)(rowBase + m) * 1024 + n0 + (cb >> 1)) =
        *(const uint4*)((const char*)sm + idx);
  }
}

__global__ __launch_bounds__(256, 4) void gemm1_kernel(
    const unsigned short* __restrict__ xbf, const unsigned short* __restrict__ w1T,
    const float* __restrict__ b1, const int* __restrict__ tileExpert,
    const int* __restrict__ tileRowBase, const int* __restrict__ rowTok,
    unsigned short* __restrict__ h) {
  __shared__ __align__(16) unsigned short sm[16384];
  moe_gemm_body<true, true>(xbf, w1T, b1, tileExpert, tileRowBase, rowTok, h, sm);
}

__global__ __launch_bounds__(256, 4) void gemm2_kernel(
    const unsigned short* __restrict__ h, const unsigned short* __restrict__ w2T,
    const float* __restrict__ b2, const int* __restrict__ tileExpert,
    const int* __restrict__ tileRowBase, const int* __restrict__ rowTok,
    unsigned short* __restrict__ y) {
  __shared__ __align__(16) unsigned short sm[16384];
  moe_gemm_body<false, false>(h, w2T, b2, tileExpert, tileRowBase, rowTok, y, sm);
}

// ---------------- combine: out[t] = w0*y[r0] + w1*y[r1] ----------------
__global__ __launch_bounds__(256) void combine_kernel(const unsigned short* __restrict__ y,
                                                      const int* __restrict__ topRow,
                                                      const float* __restrict__ topW,
                                                      float* __restrict__ out) {
  int tid = threadIdx.x;
  int wv = tid >> 6, lane = tid & 63;
  int t = blockIdx.x * 4 + wv;
  int r0 = topRow[t * 2 + 0], r1 = topRow[t * 2 + 1];
  float w0 = topW[t * 2 + 0], w1 = topW[t * 2 + 1];
  const unsigned short* p0 = y + (size_t)r0 * 1024 + lane * 16;
  const unsigned short* p1 = y + (size_t)r1 * 1024 + lane * 16;
  float* op = out + (size_t)t * 1024 + lane * 16;
  #pragma unroll
  for (int hh = 0; hh < 2; ++hh) {
    union { uint4 v; unsigned short s[8]; } a, b;
    a.v = *(const uint4*)(p0 + hh * 8);
    b.v = *(const uint4*)(p1 + hh * 8);
    float o[8];
    #pragma unroll
    for (int j = 0; j < 8; ++j)
      o[j] = w0 * bf2f(a.s[j]) + w1 * bf2f(b.s[j]);
    *(float4*)(op + hh * 8) = *(float4*)&o[0];
    *(float4*)(op + hh * 8 + 4) = *(float4*)&o[4];
  }
}

extern "C" void kernel_launch(void* const* d_in, const int* in_sizes, int n_in,
                              void* d_out, int out_size, void* d_ws, size_t ws_size,
                              hipStream_t stream) {
  const float* x  = (const float*)d_in[0];
  const float* gw = (const float*)d_in[1];
  const float* w1 = (const float*)d_in[2];
  const float* b1 = (const float*)d_in[3];
  const float* w2 = (const float*)d_in[4];
  const float* b2 = (const float*)d_in[5];
  float* out = (float*)d_out;

  char* ws = (char*)d_ws;
  int* tileExpert  = (int*)ws;                            // 136
  int* tileRowBase = tileExpert + MAXT;                   // 136
  int* topE        = tileRowBase + MAXT;                  // 16384
  int* topRow      = topE + 16384;                        // 16384
  float* topW      = (float*)(topRow + 16384);            // 16384
  int* rowTok      = (int*)(ws + (256 << 10));            // 17408 ints
  unsigned short* xbf  = (unsigned short*)(ws + (512 << 10));
  unsigned short* w1T  = xbf + (size_t)NTOK * DIN;
  unsigned short* w2T  = w1T + (size_t)NEXP * DIN * DEXP;
  unsigned short* hbuf = w2T + (size_t)NEXP * DEXP * DEXP;
  unsigned short* ybuf = hbuf + (size_t)MAXROWS * DEXP;

  prep_kernel<<<2048 + 4096 + 17, 256, 0, stream>>>(x, gw, w1, w2, xbf, w1T, w2T,
                                                    out + (size_t)NTOK * DEXP,
                                                    topE, topW, rowTok);
  slot_kernel<<<1, 1024, 0, stream>>>(topE, topRow, rowTok, tileExpert, tileRowBase);
  gemm1_kernel<<<dim3(8, MAXT), 256, 0, stream>>>(xbf, w1T, b1, tileExpert,
                                                  tileRowBase, rowTok, hbuf);
  gemm2_kernel<<<dim3(8, MAXT), 256, 0, stream>>>(hbuf, w2T, b2, tileExpert,
                                                  tileRowBase, rowTok, ybuf);
  combine_kernel<<<NTOK / 4, 256, 0, stream>>>(ybuf, topRow, topW, out);
}